// Round 8
// baseline (246.715 us; speedup 1.0000x reference)
//
#include <hip/hip_runtime.h>
#include <math.h>

// Problem constants
constexpr int B = 2, C = 256, H = 56, W = 96;
constexpr int HW = H * W;

// int8 quantization: scale 127/6 for both fmaps; dots rescaled at the end.
#define SQ 21.166666f                    // 127/6
constexpr float SCL = 36.0f / (127.0f * 127.0f * 16.0f);  // 1/(SQ^2 * sqrt(C))

typedef int int4v __attribute__((ext_vector_type(4)));

// Workspace layout (byte offsets, all 16B-aligned)
constexpr size_t F1T_B = 0;                                   // i8 [B,HW,C]
constexpr size_t L0_B  = (size_t)B * HW * C;                  // i8 [B,HW,C]      @ 2,752,512
constexpr size_t L1_B  = L0_B + (size_t)B * HW * C;           // i8 [B,28*48,C]   @ 5,505,024
constexpr size_t L2_B  = L1_B + (size_t)B * 28 * 48 * C;      // i8 [B,14*24,C]
constexpr size_t L3_B  = L2_B + (size_t)B * 14 * 24 * C;      // i8 [B,7*12,C]
constexpr size_t STG_B = L3_B + (size_t)B * 7 * 12 * C;       // fp16 [B,HW,324]  @ 6,408,192
constexpr size_t OUT0_ELEMS = (size_t)B * 324 * HW;

static __device__ __forceinline__ unsigned short pack_i8x2(float a, float b) {
    int ia = (int)rintf(a); ia = ia < -127 ? -127 : (ia > 127 ? 127 : ia);
    int ib = (int)rintf(b); ib = ib < -127 ? -127 : (ib > 127 ? 127 : ib);
    return (unsigned short)((ia & 0xFF) | ((ib & 0xFF) << 8));
}

// [B,C,HW] fp32 -> channel-last int8 (scale SQ) for both fmap1 and fmap2.
// grid (HW/32, C/64, 2*B), block (32,8). Tile: 64 ch x 32 q.
__global__ void transpose_in(const float* __restrict__ fmap1,
                             const float* __restrict__ fmap2,
                             char* __restrict__ ws) {
    __shared__ float tile[64][33];
    int z = blockIdx.z;
    int b = z & 1, m = z >> 1;                 // m=0: fmap1, m=1: fmap2
    const float* src = m ? fmap2 : fmap1;
    unsigned short* dst = (unsigned short*)(ws + (m ? L0_B : F1T_B));
    int c0 = blockIdx.y * 64, q0 = blockIdx.x * 32;
    int tx = threadIdx.x, ty = threadIdx.y;
#pragma unroll
    for (int r = 0; r < 8; ++r) {
        int cl = ty + r * 8;
        tile[cl][tx] = src[((size_t)(b * C + c0 + cl)) * HW + q0 + tx];
    }
    __syncthreads();
#pragma unroll
    for (int r = 0; r < 4; ++r) {
        int pl = ty + r * 8;
        dst[((size_t)b * HW + q0 + pl) * 128 + (c0 >> 1) + tx] =
            pack_i8x2(tile[2 * tx][pl] * SQ, tile[2 * tx + 1][pl] * SQ);
    }
}

// Build pyramid levels 1..3 directly from i8 L0; one thread per channel PAIR.
constexpr int NP1 = B * 28 * 48 * C / 2;   // 344,064
constexpr int NP2 = B * 14 * 24 * C / 2;   //  86,016
constexpr int NP3 = B * 7 * 12 * C / 2;    //  21,504
__global__ void build_pools(char* __restrict__ ws) {
    const unsigned short* L0p = (const unsigned short*)(ws + L0_B);
    int t = blockIdx.x * 256 + threadIdx.x;
    int l, tl;
    if (t < NP1)             { l = 1; tl = t; }
    else if (t < NP1 + NP2)  { l = 2; tl = t - NP1; }
    else                     { l = 3; tl = t - NP1 - NP2; }
    int Wo = W >> l, Ho = H >> l, S = 1 << l;
    int c2 = tl & 127;
    int r = tl >> 7;
    int x = r % Wo; r /= Wo;
    int y = r % Ho;
    int b = r / Ho;
    int sx = 0, sy = 0;
    for (int dy = 0; dy < S; ++dy)
        for (int dx = 0; dx < S; ++dx) {
            unsigned short v = L0p[((size_t)(b * H + y * S + dy) * W + x * S + dx) * 128 + c2];
            sx += (int)(char)(v & 0xFF);
            sy += (int)(char)(v >> 8);
        }
    float inv = 1.0f / (S * S);
    unsigned short* dst = (unsigned short*)(ws + (l == 1 ? L1_B : (l == 2 ? L2_B : L3_B)));
    dst[tl] = pack_i8x2((float)sx * inv, (float)sy * inv);
}

// One block per query pixel; wave l = pyramid level l. XCD swizzle (b=blk&1).
// MFMA formulation: per chunk of 16 positions, D(16x16) = A(16pos x 64ch) x
// B(64ch x 16) with f1 in B column 0; 4 chained mfma_i32_16x16x64_i8 cover
// K=256. Lane roles: m=lane&15 (position / B-col), kg=lane>>4 (K-subgroup).
// A[m][k=kg*16+j] = lane's 16B load; D: col=lane&15, row=kg*4+reg.
// OOB positions: clamped (safe) loads, zeroed at the Dsh write via ballot mask.
__global__ __launch_bounds__(256) void corr_lookup(
    const float* __restrict__ coords, const char* __restrict__ ws,
    _Float16* __restrict__ stage) {
    int q = blockIdx.x;
    int b = q & 1;
    int pos = q >> 1;
    int w = pos % W;
    int h = pos / W;
    int tid = threadIdx.x;

    __shared__ float Dsh[4][100];

    int wave = tid >> 6, lane = tid & 63;
    int m = lane & 15;     // A row (position-within-chunk) / D col
    int kg = lane >> 4;    // K subgroup

    // B operand: f1 in column 0 only. Lane holds B[k=c*64+kg*16+j][n=m].
    const int4v* f1p = (const int4v*)(ws + F1T_B + ((size_t)b * HW + h * W + w) * C);
    int4v zero = {0, 0, 0, 0};
    int4v Bf[4];
#pragma unroll
    for (int c = 0; c < 4; ++c) {
        int4v v = f1p[c * 4 + kg];
        Bf[c] = (m == 0) ? v : zero;
    }

    int l = wave;
    int Hl = H >> l, Wl = W >> l;
    size_t off = (l == 0 ? L0_B : (l == 1 ? L1_B : (l == 2 ? L2_B : L3_B)));
    const char* base8 = ws + off + (size_t)b * Hl * Wl * C;

    float cx = coords[((size_t)(b * 2 + 0)) * HW + h * W + w];
    float cy = coords[((size_t)(b * 2 + 1)) * HW + h * W + w];
    float scale = 1.0f / (float)(1 << l);
    float fx = cx * scale, fy = cy * scale;
    float fxf = floorf(fx), fyf = floorf(fy);
    float wx = fx - fxf, wy = fy - fyf;
    int ix = (int)fxf, iy = (int)fyf;

    // per-lane position p = c*16 + m; xx=p%10, yy=p/10 kept incrementally
    int xx = m % 10;
    int yy = m / 10;

#pragma unroll
    for (int c = 0; c < 7; ++c) {
        int p = c * 16 + m;
        int x = ix - 4 + xx;
        int y = iy - 4 + yy;
        bool valid = ((unsigned)x < (unsigned)Wl) & ((unsigned)y < (unsigned)Hl) & (p < 100);
        int xc = min(max(x, 0), Wl - 1);
        int yc = min(max(y, 0), Hl - 1);
        const int4v* cp = (const int4v*)(base8 + ((size_t)(yc * Wl + xc)) * 256 + kg * 16);
        int4v A0 = cp[0];     // ch kg*16 + 0..15
        int4v A1 = cp[4];     // + 64
        int4v A2 = cp[8];     // + 128
        int4v A3 = cp[12];    // + 192
        unsigned long long msk = __ballot(valid);
        int4v d;
        d = __builtin_amdgcn_mfma_i32_16x16x64_i8(A0, Bf[0], zero, 0, 0, 0);
        d = __builtin_amdgcn_mfma_i32_16x16x64_i8(A1, Bf[1], d, 0, 0, 0);
        d = __builtin_amdgcn_mfma_i32_16x16x64_i8(A2, Bf[2], d, 0, 0, 0);
        d = __builtin_amdgcn_mfma_i32_16x16x64_i8(A3, Bf[3], d, 0, 0, 0);
        if (m == 0) {
#pragma unroll
            for (int r = 0; r < 4; ++r) {
                int row = kg * 4 + r;
                int pp = c * 16 + row;
                if (pp < 100)
                    Dsh[wave][pp] = ((msk >> row) & 1) ? (float)d[r] * SCL : 0.f;
            }
        }
        xx += 6;
        yy += 1;
        int carry = (xx >= 10);
        xx -= carry ? 10 : 0;
        yy += carry;
    }
    __syncthreads();

    // 81 bilinear combines; o: x-offset = o/9 (slow), y-offset = o%9 (fast)
    size_t bse = ((size_t)b * HW + h * W + w) * 324 + l * 81;
    for (int o = lane; o < 81; o += 64) {
        int xo = o / 9;
        int yo = o - xo * 9;
        float v00 = Dsh[wave][yo * 10 + xo];
        float v01 = Dsh[wave][yo * 10 + xo + 1];
        float v10 = Dsh[wave][(yo + 1) * 10 + xo];
        float v11 = Dsh[wave][(yo + 1) * 10 + xo + 1];
        float s = (1.f - wy) * ((1.f - wx) * v00 + wx * v01)
                +        wy  * ((1.f - wx) * v10 + wx * v11);
        stage[bse + o] = (_Float16)s;
    }
}

// Fused tail: blocks [0,3696) transpose stage->out0; blocks [3696,4592) convex upsample.
constexpr int T_BLOCKS = 168 * 11 * B;   // 3696
__global__ __launch_bounds__(256) void tail_kernel(
    const _Float16* __restrict__ stage, const float* __restrict__ flow,
    const float* __restrict__ mask, float* __restrict__ out0,
    float* __restrict__ out1) {
    __shared__ float smem[72 * 96 + 2 * 3 * 98];
    int blk = blockIdx.x;
    int tid = threadIdx.x;

    if (blk < T_BLOCKS) {
        float (*tile)[33] = (float(*)[33])smem;
        int b = blk / (168 * 11);
        int rem = blk % (168 * 11);
        int by = rem / 168, bx = rem % 168;
        int ch0 = by * 32, q0 = bx * 32;
        int tx = tid & 31, ty = tid >> 5;
#pragma unroll
        for (int r = 0; r < 4; ++r) {
            int pl = ty + r * 8;
            if (ch0 + tx < 324)
                tile[pl][tx] = (float)stage[((size_t)b * HW + q0 + pl) * 324 + ch0 + tx];
        }
        __syncthreads();
#pragma unroll
        for (int r = 0; r < 4; ++r) {
            int chl = ty + r * 8;
            if (ch0 + chl < 324)
                out0[((size_t)(b * 324 + ch0 + chl)) * HW + q0 + tx] = tile[tx][chl];
        }
        return;
    }

    float* msk = smem;               // 72*96
    float* fst = smem + 72 * 96;     // 2*3*98
    int cb = blk - T_BLOCKS;
    int i = cb & 7;
    int r = cb >> 3;
    int h = r % H;
    int b = r / H;

    for (int idx = tid; idx < 72 * 96; idx += 256) {
        int row = idx / 96, wc = idx - row * 96;
        int k = row >> 3, j = row & 7;
        int gl = k * 64 + i * 8 + j;
        msk[idx] = mask[((size_t)(b * 576 + gl)) * HW + h * W + wc];
    }
    for (int idx = tid; idx < 588; idx += 256) {
        int ch = idx / 294;
        int rem2 = idx - ch * 294;
        int rr = rem2 / 98;
        int xw = rem2 - rr * 98;
        int hh = h + rr - 1, ww = xw - 1;
        float v = 0.f;
        if (hh >= 0 && hh < H && ww >= 0 && ww < W)
            v = 8.0f * flow[((size_t)(b * 2 + ch)) * HW + hh * W + ww];
        fst[idx] = v;
    }
    __syncthreads();

#pragma unroll
    for (int rr = 0; rr < 3; ++rr) {
        int col = tid + rr * 256;    // 0..767
        int w = col >> 3, j = col & 7;
        float m[9], mx = -1e30f;
#pragma unroll
        for (int k = 0; k < 9; ++k) {
            m[k] = msk[(k * 8 + j) * 96 + w];
            mx = fmaxf(mx, m[k]);
        }
        float sum = 0.f;
#pragma unroll
        for (int k = 0; k < 9; ++k) {
            m[k] = __expf(m[k] - mx);
            sum += m[k];
        }
        float inv = 1.0f / sum;
        float a0 = 0.f, a1 = 0.f;
#pragma unroll
        for (int k = 0; k < 9; ++k) {
            int ki = k / 3, kj = k - ki * 3;
            float wgt = m[k] * inv;
            a0 = fmaf(wgt, fst[0 * 294 + ki * 98 + w + kj], a0);
            a1 = fmaf(wgt, fst[1 * 294 + ki * 98 + w + kj], a1);
        }
        size_t row8 = (size_t)8 * h + i;
        out1[((size_t)(b * 2 + 0) * 448 + row8) * 768 + col] = a0;
        out1[((size_t)(b * 2 + 1) * 448 + row8) * 768 + col] = a1;
    }
}

extern "C" void kernel_launch(void* const* d_in, const int* in_sizes, int n_in,
                              void* d_out, int out_size, void* d_ws, size_t ws_size,
                              hipStream_t stream) {
    const float* fmap1  = (const float*)d_in[0];
    const float* fmap2  = (const float*)d_in[1];
    const float* coords = (const float*)d_in[2];
    const float* flow   = (const float*)d_in[3];
    const float* maskp  = (const float*)d_in[4];
    float* out = (float*)d_out;
    char* ws = (char*)d_ws;
    _Float16* stage = (_Float16*)(ws + STG_B);

    transpose_in<<<dim3(HW / 32, C / 64, 2 * B), dim3(32, 8), 0, stream>>>(fmap1, fmap2, ws);
    build_pools<<<(NP1 + NP2 + NP3) / 256, 256, 0, stream>>>(ws);
    corr_lookup<<<B * HW, 256, 0, stream>>>(coords, ws, stage);
    tail_kernel<<<T_BLOCKS + B * H * 8, 256, 0, stream>>>(stage, flow, maskp, out, out + OUT0_ELEMS);
}

// Round 9
// 158.019 us; speedup vs baseline: 1.5613x; 1.5613x over previous
//
#include <hip/hip_runtime.h>
#include <math.h>

// Problem constants
constexpr int B = 2, C = 256, H = 56, W = 96;
constexpr int HW = H * W;

// int8 quantization: scale 127/6 for both fmaps; dots rescaled at the end.
#define SQ 21.166666f                    // 127/6
constexpr float SCL = 36.0f / (127.0f * 127.0f * 16.0f);  // 1/(SQ^2 * sqrt(C))

typedef int int4v __attribute__((ext_vector_type(4)));

// Workspace layout (byte offsets, all 16B-aligned)
constexpr size_t F1T_B = 0;                                   // i8 [B,HW,C]
constexpr size_t L0_B  = (size_t)B * HW * C;                  // i8 [B,HW,C]      @ 2,752,512
constexpr size_t L1_B  = L0_B + (size_t)B * HW * C;           // i8 [B,28*48,C]   @ 5,505,024
constexpr size_t L2_B  = L1_B + (size_t)B * 28 * 48 * C;      // i8 [B,14*24,C]
constexpr size_t L3_B  = L2_B + (size_t)B * 14 * 24 * C;      // i8 [B,7*12,C]
constexpr size_t STG_B = L3_B + (size_t)B * 7 * 12 * C;       // fp16 [B,HW,324]  @ 6,408,192
constexpr size_t OUT0_ELEMS = (size_t)B * 324 * HW;

static __device__ __forceinline__ int dot4acc(int a, int b, int c) {
#if __has_builtin(__builtin_amdgcn_sdot4)
    return __builtin_amdgcn_sdot4(a, b, c, false);
#else
    c += (int)(char)(a) * (int)(char)(b);
    c += (int)(char)(a >> 8) * (int)(char)(b >> 8);
    c += (int)(char)(a >> 16) * (int)(char)(b >> 16);
    c += (int)(char)(a >> 24) * (int)(char)(b >> 24);
    return c;
#endif
}

// Sum over the 8-lane group via DPP (VALU pipe, no DS unit):
// xor1 (quad_perm [1,0,3,2]=0xB1), xor2 (quad_perm [2,3,0,1]=0x4E), then
// row_half_mirror (0x141, lane^7 — valid since quads are uniform by then).
static __device__ __forceinline__ int group8_sum(int s) {
#if __has_builtin(__builtin_amdgcn_mov_dpp)
    s += __builtin_amdgcn_mov_dpp(s, 0xB1, 0xF, 0xF, true);
    s += __builtin_amdgcn_mov_dpp(s, 0x4E, 0xF, 0xF, true);
    s += __builtin_amdgcn_mov_dpp(s, 0x141, 0xF, 0xF, true);
    return s;
#else
    s += __shfl_xor(s, 1);
    s += __shfl_xor(s, 2);
    s += __shfl_xor(s, 4);
    return s;
#endif
}

static __device__ __forceinline__ unsigned short pack_i8x2(float a, float b) {
    int ia = (int)rintf(a); ia = ia < -127 ? -127 : (ia > 127 ? 127 : ia);
    int ib = (int)rintf(b); ib = ib < -127 ? -127 : (ib > 127 ? 127 : ib);
    return (unsigned short)((ia & 0xFF) | ((ib & 0xFF) << 8));
}

// [B,C,HW] fp32 -> channel-last int8 (scale SQ) for both fmap1 and fmap2.
// grid (HW/32, C/64, 2*B), block (32,8). Tile: 64 ch x 32 q.
__global__ void transpose_in(const float* __restrict__ fmap1,
                             const float* __restrict__ fmap2,
                             char* __restrict__ ws) {
    __shared__ float tile[64][33];
    int z = blockIdx.z;
    int b = z & 1, m = z >> 1;                 // m=0: fmap1, m=1: fmap2
    const float* src = m ? fmap2 : fmap1;
    unsigned short* dst = (unsigned short*)(ws + (m ? L0_B : F1T_B));
    int c0 = blockIdx.y * 64, q0 = blockIdx.x * 32;
    int tx = threadIdx.x, ty = threadIdx.y;
#pragma unroll
    for (int r = 0; r < 8; ++r) {
        int cl = ty + r * 8;
        tile[cl][tx] = src[((size_t)(b * C + c0 + cl)) * HW + q0 + tx];
    }
    __syncthreads();
#pragma unroll
    for (int r = 0; r < 4; ++r) {
        int pl = ty + r * 8;
        dst[((size_t)b * HW + q0 + pl) * 128 + (c0 >> 1) + tx] =
            pack_i8x2(tile[2 * tx][pl] * SQ, tile[2 * tx + 1][pl] * SQ);
    }
}

// Build pyramid levels 1..3 directly from i8 L0; one thread per channel PAIR.
constexpr int NP1 = B * 28 * 48 * C / 2;   // 344,064
constexpr int NP2 = B * 14 * 24 * C / 2;   //  86,016
constexpr int NP3 = B * 7 * 12 * C / 2;    //  21,504
__global__ void build_pools(char* __restrict__ ws) {
    const unsigned short* L0p = (const unsigned short*)(ws + L0_B);
    int t = blockIdx.x * 256 + threadIdx.x;
    int l, tl;
    if (t < NP1)             { l = 1; tl = t; }
    else if (t < NP1 + NP2)  { l = 2; tl = t - NP1; }
    else                     { l = 3; tl = t - NP1 - NP2; }
    int Wo = W >> l, Ho = H >> l, S = 1 << l;
    int c2 = tl & 127;
    int r = tl >> 7;
    int x = r % Wo; r /= Wo;
    int y = r % Ho;
    int b = r / Ho;
    int sx = 0, sy = 0;
    for (int dy = 0; dy < S; ++dy)
        for (int dx = 0; dx < S; ++dx) {
            unsigned short v = L0p[((size_t)(b * H + y * S + dy) * W + x * S + dx) * 128 + c2];
            sx += (int)(char)(v & 0xFF);
            sy += (int)(char)(v >> 8);
        }
    float inv = 1.0f / (S * S);
    unsigned short* dst = (unsigned short*)(ws + (l == 1 ? L1_B : (l == 2 ? L2_B : L3_B)));
    dst[tl] = pack_i8x2((float)sx * inv, (float)sy * inv);
}

// One block per query pixel; wave l = pyramid level l. XCD swizzle (b=blk&1).
// 8 groups x 8 lanes; group = one position dot (32 B i8/lane, coalesced).
// PREFETCH phase issues all 26 int4 loads (zero-init, predicated) so no
// iteration's compute chain waits on memory; COMPUTE phase: 8x sdot4 in two
// chains + 3-op DPP reduce (VALU pipe — DS unit unused in the hot loop).
__global__ __launch_bounds__(256) void corr_lookup(
    const float* __restrict__ coords, const char* __restrict__ ws,
    _Float16* __restrict__ stage) {
    int q = blockIdx.x;
    int b = q & 1;
    int pos = q >> 1;
    int w = pos % W;
    int h = pos / W;
    int tid = threadIdx.x;

    __shared__ float Dsh[4][100];

    int wave = tid >> 6, lane = tid & 63, u = lane & 7, grp = lane >> 3;

    // f1 fragment: 32 contiguous channels per lane (32 B = 2x int4)
    const int4v* ap = (const int4v*)(ws + F1T_B + ((size_t)b * HW + h * W + w) * C);
    int4v A0 = ap[2 * u], A1 = ap[2 * u + 1];

    int l = wave;
    int Hl = H >> l, Wl = W >> l;
    size_t off = (l == 0 ? L0_B : (l == 1 ? L1_B : (l == 2 ? L2_B : L3_B)));
    const char* base8 = ws + off + (size_t)b * Hl * Wl * C;

    float cx = coords[((size_t)(b * 2 + 0)) * HW + h * W + w];
    float cy = coords[((size_t)(b * 2 + 1)) * HW + h * W + w];
    float scale = 1.0f / (float)(1 << l);
    float fx = cx * scale, fy = cy * scale;
    float fxf = floorf(fx), fyf = floorf(fy);
    float wx = fx - fxf, wy = fy - fyf;
    int ix = (int)fxf, iy = (int)fyf;

    // p = it*8 + grp; xx = p%10, yy via y; maintained incrementally
    int xx = grp;
    int x = ix - 4 + grp;
    int y = iy - 4;

    int4v Lo[13], Hi[13];
    const int4v zero = {0, 0, 0, 0};

#pragma unroll
    for (int it = 0; it < 13; ++it) {
        bool live = (it < 12) | (grp < 4);     // p < 100
        Lo[it] = zero;
        Hi[it] = zero;
        if (live && (unsigned)x < (unsigned)Wl && (unsigned)y < (unsigned)Hl) {
            const int4v* cp = (const int4v*)(base8 + ((size_t)(y * Wl + x)) * C + u * 32);
            Lo[it] = cp[0];
            Hi[it] = cp[1];
        }
        xx += 8;
        int carry = (xx >= 10);
        xx -= carry ? 10 : 0;
        x += carry ? -2 : 8;
        y += carry;
    }

#pragma unroll
    for (int it = 0; it < 13; ++it) {
        bool live = (it < 12) | (grp < 4);
        int s0 = 0, s1 = 0;
        s0 = dot4acc(Lo[it].x, A0.x, s0);
        s1 = dot4acc(Lo[it].y, A0.y, s1);
        s0 = dot4acc(Lo[it].z, A0.z, s0);
        s1 = dot4acc(Lo[it].w, A0.w, s1);
        s0 = dot4acc(Hi[it].x, A1.x, s0);
        s1 = dot4acc(Hi[it].y, A1.y, s1);
        s0 = dot4acc(Hi[it].z, A1.z, s0);
        s1 = dot4acc(Hi[it].w, A1.w, s1);
        int s = group8_sum(s0 + s1);
        if (u == 0 && live) Dsh[wave][it * 8 + grp] = (float)s * SCL;
    }
    __syncthreads();

    // 81 bilinear combines; o: x-offset = o/9 (slow), y-offset = o%9 (fast)
    size_t bse = ((size_t)b * HW + h * W + w) * 324 + l * 81;
    for (int o = lane; o < 81; o += 64) {
        int xo = o / 9;
        int yo = o - xo * 9;
        float v00 = Dsh[wave][yo * 10 + xo];
        float v01 = Dsh[wave][yo * 10 + xo + 1];
        float v10 = Dsh[wave][(yo + 1) * 10 + xo];
        float v11 = Dsh[wave][(yo + 1) * 10 + xo + 1];
        float s = (1.f - wy) * ((1.f - wx) * v00 + wx * v01)
                +        wy  * ((1.f - wx) * v10 + wx * v11);
        stage[bse + o] = (_Float16)s;
    }
}

// Fused tail: blocks [0,3696) transpose stage->out0; blocks [3696,4592) convex upsample.
constexpr int T_BLOCKS = 168 * 11 * B;   // 3696
__global__ __launch_bounds__(256) void tail_kernel(
    const _Float16* __restrict__ stage, const float* __restrict__ flow,
    const float* __restrict__ mask, float* __restrict__ out0,
    float* __restrict__ out1) {
    __shared__ float smem[72 * 96 + 2 * 3 * 98];
    int blk = blockIdx.x;
    int tid = threadIdx.x;

    if (blk < T_BLOCKS) {
        float (*tile)[33] = (float(*)[33])smem;
        int b = blk / (168 * 11);
        int rem = blk % (168 * 11);
        int by = rem / 168, bx = rem % 168;
        int ch0 = by * 32, q0 = bx * 32;
        int tx = tid & 31, ty = tid >> 5;
#pragma unroll
        for (int r = 0; r < 4; ++r) {
            int pl = ty + r * 8;
            if (ch0 + tx < 324)
                tile[pl][tx] = (float)stage[((size_t)b * HW + q0 + pl) * 324 + ch0 + tx];
        }
        __syncthreads();
#pragma unroll
        for (int r = 0; r < 4; ++r) {
            int chl = ty + r * 8;
            if (ch0 + chl < 324)
                out0[((size_t)(b * 324 + ch0 + chl)) * HW + q0 + tx] = tile[tx][chl];
        }
        return;
    }

    float* msk = smem;               // 72*96
    float* fst = smem + 72 * 96;     // 2*3*98
    int cb = blk - T_BLOCKS;
    int i = cb & 7;
    int r = cb >> 3;
    int h = r % H;
    int b = r / H;

    for (int idx = tid; idx < 72 * 96; idx += 256) {
        int row = idx / 96, wc = idx - row * 96;
        int k = row >> 3, j = row & 7;
        int gl = k * 64 + i * 8 + j;
        msk[idx] = mask[((size_t)(b * 576 + gl)) * HW + h * W + wc];
    }
    for (int idx = tid; idx < 588; idx += 256) {
        int ch = idx / 294;
        int rem2 = idx - ch * 294;
        int rr = rem2 / 98;
        int xw = rem2 - rr * 98;
        int hh = h + rr - 1, ww = xw - 1;
        float v = 0.f;
        if (hh >= 0 && hh < H && ww >= 0 && ww < W)
            v = 8.0f * flow[((size_t)(b * 2 + ch)) * HW + hh * W + ww];
        fst[idx] = v;
    }
    __syncthreads();

#pragma unroll
    for (int rr = 0; rr < 3; ++rr) {
        int col = tid + rr * 256;    // 0..767
        int w = col >> 3, j = col & 7;
        float m[9], mx = -1e30f;
#pragma unroll
        for (int k = 0; k < 9; ++k) {
            m[k] = msk[(k * 8 + j) * 96 + w];
            mx = fmaxf(mx, m[k]);
        }
        float sum = 0.f;
#pragma unroll
        for (int k = 0; k < 9; ++k) {
            m[k] = __expf(m[k] - mx);
            sum += m[k];
        }
        float inv = 1.0f / sum;
        float a0 = 0.f, a1 = 0.f;
#pragma unroll
        for (int k = 0; k < 9; ++k) {
            int ki = k / 3, kj = k - ki * 3;
            float wgt = m[k] * inv;
            a0 = fmaf(wgt, fst[0 * 294 + ki * 98 + w + kj], a0);
            a1 = fmaf(wgt, fst[1 * 294 + ki * 98 + w + kj], a1);
        }
        size_t row8 = (size_t)8 * h + i;
        out1[((size_t)(b * 2 + 0) * 448 + row8) * 768 + col] = a0;
        out1[((size_t)(b * 2 + 1) * 448 + row8) * 768 + col] = a1;
    }
}

extern "C" void kernel_launch(void* const* d_in, const int* in_sizes, int n_in,
                              void* d_out, int out_size, void* d_ws, size_t ws_size,
                              hipStream_t stream) {
    const float* fmap1  = (const float*)d_in[0];
    const float* fmap2  = (const float*)d_in[1];
    const float* coords = (const float*)d_in[2];
    const float* flow   = (const float*)d_in[3];
    const float* maskp  = (const float*)d_in[4];
    float* out = (float*)d_out;
    char* ws = (char*)d_ws;
    _Float16* stage = (_Float16*)(ws + STG_B);

    transpose_in<<<dim3(HW / 32, C / 64, 2 * B), dim3(32, 8), 0, stream>>>(fmap1, fmap2, ws);
    build_pools<<<(NP1 + NP2 + NP3) / 256, 256, 0, stream>>>(ws);
    corr_lookup<<<B * HW, 256, 0, stream>>>(coords, ws, stage);
    tail_kernel<<<T_BLOCKS + B * H * 8, 256, 0, stream>>>(stage, flow, maskp, out, out + OUT0_ELEMS);
}